// Round 16
// baseline (332.722 us; speedup 1.0000x reference)
//
#include <hip/hip_runtime.h>
#include <hip/hip_cooperative_groups.h>
#include <hip/hip_fp16.h>
#include <math.h>

namespace cg = cooperative_groups;

#define N_NODES 50000
#define NE      800000
#define INC     128
#define F1      128     // HEADS*HID
#define HEADS   8
#define HID     16
#define OUTC    16
#define NEG     0.2f
#define NBKT    196      // (N_NODES+255)>>8
#define NPART   128      // edge-stripe blocks (blocks 128..195 do weight prep)

union H4 { ushort4 u; __half h[4]; };
union H8 { uint4 u; __half h[8]; };

typedef _Float16 f16x8 __attribute__((ext_vector_type(8)));
typedef float    f32x4 __attribute__((ext_vector_type(4)));

// ===== ONE cooperative kernel: hist + weight prep + scan + scatter + sort ===
// 196 blocks x 256 threads, all co-resident; 5 grid syncs.
__global__ __launch_bounds__(256) void csr_build_kernel(
    const int* __restrict__ ei, int* __restrict__ cnt, int* __restrict__ bsum,
    int* __restrict__ tmp, int* __restrict__ rowstart, int* __restrict__ csr,
    const float* __restrict__ W1, const float* __restrict__ as1,
    const float* __restrict__ ad1, __half* __restrict__ W1t,
    __half* __restrict__ waT)
{
    cg::grid_group grid = cg::this_grid();
    __shared__ int sh[256];
    __shared__ int cur[NBKT];
    int b = blockIdx.x, tid = threadIdx.x;

    // ---- Phase A: blocks 0..127 hist their edge stripe; 128..195 weight prep
    if (b < NPART) {
        for (int i = tid; i < NBKT; i += 256) cur[i] = 0;
        __syncthreads();
        for (int e = b * 256 + tid; e < NE; e += NPART * 256)
            atomicAdd(&cur[ei[NE + e] >> 8], 1);
        __syncthreads();
        for (int i = tid; i < NBKT; i += 256) cnt[i * NPART + b] = cur[i];
    } else {
        for (int u = b - NPART; u < 72; u += NBKT - NPART) {
            if (u < 64) {                       // W1 transpose to fp16
                int i = u * 256 + tid;
                int k = i >> 7, nn = i & 127;
                W1t[nn * 128 + k] = __float2half(W1[k * 128 + nn]);
            } else {                            // folded attention matrix Wa
                int i = (u - 64) * 256 + tid;   // 0..2047
                int col = i & 15, k = i >> 4;
                int hh = col & 7;
                const float* av = (col < 8) ? as1 : ad1;
                float s = 0.f;
                #pragma unroll
                for (int cc = 0; cc < 16; ++cc)
                    s += W1[k * 128 + hh * 16 + cc] * av[hh * 16 + cc];
                waT[col * 128 + k] = __float2half(s);
            }
        }
    }
    grid.sync();

    // ---- Phase B1: block b exclusive-scans bin-row b (NPART ints), total->bsum
    {
        int v = (tid < NPART) ? cnt[b * NPART + tid] : 0;
        sh[tid] = v; __syncthreads();
        for (int off = 1; off < 256; off <<= 1) {
            int t = (tid >= off) ? sh[tid - off] : 0;
            __syncthreads();
            sh[tid] += t;
            __syncthreads();
        }
        if (tid < NPART) cnt[b * NPART + tid] = sh[tid] - v;   // local exclusive
        if (tid == 255) bsum[b] = sh[255];                     // row total
    }
    grid.sync();

    // ---- Phase B2: block 0 exclusive-scans bsum[NBKT]
    if (b == 0) {
        int v = (tid < NBKT) ? bsum[tid] : 0;
        sh[tid] = v; __syncthreads();
        for (int off = 1; off < 256; off <<= 1) {
            int t = (tid >= off) ? sh[tid - off] : 0;
            __syncthreads();
            sh[tid] += t;
            __syncthreads();
        }
        if (tid < NBKT) bsum[tid] = sh[tid] - v;
    }
    grid.sync();

    // ---- Phase B3: add bin base to local offsets
    if (tid < NPART) cnt[b * NPART + tid] += bsum[b];
    grid.sync();

    // ---- Phase C: blocks 0..127 scatter stripe -> tmp (LDS cursors)
    if (b < NPART) {
        for (int i = tid; i < NBKT; i += 256) cur[i] = cnt[i * NPART + b];
        __syncthreads();
        for (int e = b * 256 + tid; e < NE; e += NPART * 256) {
            int s = ei[e], d = ei[NE + e];
            int p = atomicAdd(&cur[d >> 8], 1);
            tmp[p] = s | ((d & 255) << 16);    // s in 0..15, d&255 in 16..23
        }
    }
    grid.sync();

    // ---- Phase D: block b counting-sorts bucket b -> rowstart + csr
    {
        int base = cnt[b * NPART];
        int end  = (b == NBKT - 1) ? NE : cnt[(b + 1) * NPART];
        sh[tid] = 0; __syncthreads();
        for (int i = base + tid; i < end; i += 256)
            atomicAdd(&sh[(tmp[i] >> 16) & 255], 1);
        __syncthreads();
        int v = sh[tid];
        for (int off = 1; off < 256; off <<= 1) {
            int t = (tid >= off) ? sh[tid - off] : 0;
            __syncthreads();
            sh[tid] += t;
            __syncthreads();
        }
        int excl = sh[tid] - v;
        int n = (b << 8) + tid;
        if (n <= N_NODES) rowstart[n] = base + excl;
        __syncthreads();
        sh[tid] = excl;
        __syncthreads();
        for (int i = base + tid; i < end; i += 256) {
            int e = tmp[i];
            int p = base + atomicAdd(&sh[(e >> 16) & 255], 1);
            csr[p] = e & 0xFFFF;
        }
    }
}

// ---------------- Layer 1: MFMA GEMM (x @ W1) + logits via Wa-GEMM ---------
__global__ __launch_bounds__(256) void node1_kernel(
    const float* __restrict__ x, const __half* __restrict__ W1t,
    const __half* __restrict__ waT,
    __half* __restrict__ hfeat, float* __restrict__ als, float* __restrict__ ald)
{
    __shared__ _Float16 Xh[64 * 136];    // 17.4 KB
    __shared__ _Float16 Wt[128 * 136];   // 34.8 KB (pad 8 halves/row)
    int tid = threadIdx.x;
    int n0 = blockIdx.x * 64;

    for (int idx = tid; idx < 128 * 16; idx += 256) {   // 16 x uint4 per row
        int row = idx >> 4, c8 = (idx & 15) * 8;
        *(uint4*)(&Wt[row * 136 + c8]) = ((const uint4*)W1t)[idx];
    }
    for (int idx = tid; idx < 64 * 32; idx += 256) {
        int m = idx >> 5, f4 = idx & 31;
        int n = n0 + m;
        float4 v = (n < N_NODES) ? ((const float4*)(x + (size_t)n * INC))[f4]
                                 : make_float4(0.f, 0.f, 0.f, 0.f);
        union { unsigned long long u; _Float16 h[4]; } p;
        p.h[0] = (_Float16)v.x; p.h[1] = (_Float16)v.y;
        p.h[2] = (_Float16)v.z; p.h[3] = (_Float16)v.w;
        *(unsigned long long*)(&Xh[m * 136 + f4 * 4]) = p.u;
    }
    __syncthreads();

    int wave = tid >> 6, lane = tid & 63;
    int colL = lane & 15, q = lane >> 4;
    int nb = wave * 32;

    f32x4 acc[4][2];
    #pragma unroll
    for (int mt = 0; mt < 4; ++mt)
        #pragma unroll
        for (int nt = 0; nt < 2; ++nt)
            acc[mt][nt] = (f32x4){0.f, 0.f, 0.f, 0.f};
    f32x4 acc2 = (f32x4){0.f, 0.f, 0.f, 0.f};   // logits, mt = wave

    #pragma unroll
    for (int kb = 0; kb < 4; ++kb) {
        int ko = kb * 32 + q * 8;
        f16x8 b0 = *(const f16x8*)(&Wt[(nb +  0 + colL) * 136 + ko]);
        f16x8 b1 = *(const f16x8*)(&Wt[(nb + 16 + colL) * 136 + ko]);
        #pragma unroll
        for (int mt = 0; mt < 4; ++mt) {
            f16x8 a = *(const f16x8*)(&Xh[(mt * 16 + colL) * 136 + ko]);
            acc[mt][0] = __builtin_amdgcn_mfma_f32_16x16x32_f16(a, b0, acc[mt][0], 0, 0, 0);
            acc[mt][1] = __builtin_amdgcn_mfma_f32_16x16x32_f16(a, b1, acc[mt][1], 0, 0, 0);
        }
        f16x8 bw = *(const f16x8*)(waT + colL * 128 + ko);           // global, L2-hot
        f16x8 aw = *(const f16x8*)(&Xh[(wave * 16 + colL) * 136 + ko]);
        acc2 = __builtin_amdgcn_mfma_f32_16x16x32_f16(aw, bw, acc2, 0, 0, 0);
    }

    // h stores (fp16)
    #pragma unroll
    for (int nt = 0; nt < 2; ++nt) {
        int col = nb + nt * 16 + colL;
        #pragma unroll
        for (int mt = 0; mt < 4; ++mt) {
            f32x4 d = acc[mt][nt];
            #pragma unroll
            for (int r = 0; r < 4; ++r) {
                int node = n0 + mt * 16 + q * 4 + r;
                if (node < N_NODES) hfeat[(size_t)node * F1 + col] = __float2half(d[r]);
            }
        }
    }
    // logit stores: split src/dst arrays (32B/node granularity for the gather)
    #pragma unroll
    for (int r = 0; r < 4; ++r) {
        int node = n0 + wave * 16 + q * 4 + r;
        if (node < N_NODES) {
            if (colL < 8) als[node * 8 + colL] = acc2[r];
            else          ald[node * 8 + (colL - 8)] = acc2[r];
        }
    }
}

// ------ Layer 1 gather: 16 lanes/node, 8 fp16/lane, depth-2 static pipeline -
__global__ __launch_bounds__(256) void agg1_kernel(
    const int* __restrict__ rowstart, const int* __restrict__ csr,
    const __half* __restrict__ h1, const float* __restrict__ als,
    const float* __restrict__ ald, const float* __restrict__ b1,
    __half* __restrict__ hout)
{
    int tid = threadIdx.x;
    int n = blockIdx.x * 16 + (tid >> 4);
    int lane = tid & 15;
    int c = lane * 8;
    int head = lane >> 1;
    float aldn = ald[n * 8 + head];
    float v0 = als[n * 8 + head] + aldn;
    v0 = fmaxf(v0, NEG * v0);
    float w0 = __expf(v0);
    float sum = w0;
    float a[8];
    {
        H8 hs; hs.u = *(const uint4*)(h1 + (size_t)n * F1 + c);
        #pragma unroll
        for (int i = 0; i < 8; ++i) a[i] = w0 * __half2float(hs.h[i]);
    }
    int r0 = rowstart[n], r1 = rowstart[n + 1];

    float vA = 0.f, vB = 0.f;
    H8 hA, hB; hA.u = make_uint4(0,0,0,0); hB.u = hA.u;
    int sC = 0, sD = 0;
    if (r0 < r1) {
        int s = csr[r0];
        float t = als[s * 8 + head] + aldn;
        vA = fmaxf(t, NEG * t);
        hA.u = *(const uint4*)(h1 + (size_t)s * F1 + c);
    }
    if (r0 + 1 < r1) {
        int s = csr[r0 + 1];
        float t = als[s * 8 + head] + aldn;
        vB = fmaxf(t, NEG * t);
        hB.u = *(const uint4*)(h1 + (size_t)s * F1 + c);
    }
    if (r0 + 2 < r1) sC = csr[r0 + 2];
    if (r0 + 3 < r1) sD = csr[r0 + 3];

    int k = r0;
    for (; k + 1 < r1; k += 2) {
        float vcA = vA, vcB = vB;
        H8 hcA = hA, hcB = hB;
        int sE = (k + 4 < r1) ? csr[k + 4] : 0;
        int sF = (k + 5 < r1) ? csr[k + 5] : 0;
        if (k + 2 < r1) {
            float t = als[sC * 8 + head] + aldn;
            vA = fmaxf(t, NEG * t);
            hA.u = *(const uint4*)(h1 + (size_t)sC * F1 + c);
        }
        if (k + 3 < r1) {
            float t = als[sD * 8 + head] + aldn;
            vB = fmaxf(t, NEG * t);
            hB.u = *(const uint4*)(h1 + (size_t)sD * F1 + c);
        }
        sC = sE; sD = sF;
        float wA = __expf(vcA), wB = __expf(vcB);
        sum += wA + wB;
        #pragma unroll
        for (int i = 0; i < 8; ++i) {
            a[i] = fmaf(wA, __half2float(hcA.h[i]), a[i]);
            a[i] = fmaf(wB, __half2float(hcB.h[i]), a[i]);
        }
    }
    if (k < r1) {                      // odd tail: consume slot A
        float wA = __expf(vA);
        sum += wA;
        #pragma unroll
        for (int i = 0; i < 8; ++i) a[i] = fmaf(wA, __half2float(hA.h[i]), a[i]);
    }

    float inv = 1.0f / sum;
    H8 t;
    #pragma unroll
    for (int i = 0; i < 8; ++i) {
        float o = a[i] * inv + b1[c + i];
        o = o > 0.f ? o : (__expf(o) - 1.0f);
        t.h[i] = __float2half(o);
    }
    *(uint4*)(hout + (size_t)n * F1 + c) = t.u;
}

// ---------------- Layer 2: GEMM (h1' @ W2) + logits, fp16 in/out ----------
__global__ __launch_bounds__(256) void node2_kernel(
    const __half* __restrict__ h1, const float* __restrict__ W2,
    const float* __restrict__ a_s, const float* __restrict__ a_d,
    __half* __restrict__ h2, float* __restrict__ als2, float* __restrict__ ald2)
{
    __shared__ float W2l[F1 * OUTC];   // 8 KB
    for (int i = threadIdx.x; i < F1 * OUTC; i += 256) W2l[i] = W2[i];
    __syncthreads();
    int n = blockIdx.x * blockDim.x + threadIdx.x;
    if (n >= N_NODES) return;

    float o[OUTC];
    #pragma unroll
    for (int c = 0; c < OUTC; ++c) o[c] = 0.f;
    const uint4* xr = (const uint4*)(h1 + (size_t)n * F1);
    for (int k8 = 0; k8 < 16; ++k8) {
        H8 xv; xv.u = xr[k8];
        int k = k8 * 8;
        #pragma unroll
        for (int j = 0; j < 8; ++j) {
            float xf = __half2float(xv.h[j]);
            #pragma unroll
            for (int c = 0; c < OUTC; ++c)
                o[c] = fmaf(xf, W2l[(k + j) * OUTC + c], o[c]);
        }
    }
    H8 s0, s1;
    #pragma unroll
    for (int j = 0; j < 8; ++j) { s0.h[j] = __float2half(o[j]); s1.h[j] = __float2half(o[8 + j]); }
    uint4* h2o = (uint4*)(h2 + (size_t)n * OUTC);
    h2o[0] = s0.u; h2o[1] = s1.u;
    float ps = 0.f, pd = 0.f;
    #pragma unroll
    for (int c = 0; c < OUTC; ++c) { ps += o[c] * a_s[c]; pd += o[c] * a_d[c]; }
    als2[n] = ps; ald2[n] = pd;
}

// ------ Layer 2 gather: 4 lanes/node, 4 fp16/lane, depth-2 static pipeline -
__global__ __launch_bounds__(256) void agg2_kernel(
    const int* __restrict__ rowstart, const int* __restrict__ csr,
    const __half* __restrict__ h2, const float* __restrict__ als,
    const float* __restrict__ ald, const float* __restrict__ b2,
    float* __restrict__ out)
{
    int tid = threadIdx.x;
    int n = blockIdx.x * 64 + (tid >> 2);
    if (n >= N_NODES) return;
    int c = (tid & 3) * 4;
    float aldn = ald[n];
    float v0 = als[n] + aldn;
    v0 = fmaxf(v0, NEG * v0);
    float w0 = __expf(v0);
    float sum = w0;
    H4 hs; hs.u = *(const ushort4*)(h2 + (size_t)n * OUTC + c);
    float a0 = w0 * __half2float(hs.h[0]), a1 = w0 * __half2float(hs.h[1]);
    float a2 = w0 * __half2float(hs.h[2]), a3 = w0 * __half2float(hs.h[3]);
    int r0 = rowstart[n], r1 = rowstart[n + 1];

    float vA = 0.f, vB = 0.f;
    H4 hA, hB; hA.u = make_ushort4(0,0,0,0); hB.u = hA.u;
    int sC = 0, sD = 0;
    if (r0 < r1) {
        int s = csr[r0];
        float t = als[s] + aldn;
        vA = fmaxf(t, NEG * t);
        hA.u = *(const ushort4*)(h2 + (size_t)s * OUTC + c);
    }
    if (r0 + 1 < r1) {
        int s = csr[r0 + 1];
        float t = als[s] + aldn;
        vB = fmaxf(t, NEG * t);
        hB.u = *(const ushort4*)(h2 + (size_t)s * OUTC + c);
    }
    if (r0 + 2 < r1) sC = csr[r0 + 2];
    if (r0 + 3 < r1) sD = csr[r0 + 3];

    int k = r0;
    for (; k + 1 < r1; k += 2) {
        float vcA = vA, vcB = vB;
        H4 hcA = hA, hcB = hB;
        int sE = (k + 4 < r1) ? csr[k + 4] : 0;
        int sF = (k + 5 < r1) ? csr[k + 5] : 0;
        if (k + 2 < r1) {
            float t = als[sC] + aldn;
            vA = fmaxf(t, NEG * t);
            hA.u = *(const ushort4*)(h2 + (size_t)sC * OUTC + c);
        }
        if (k + 3 < r1) {
            float t = als[sD] + aldn;
            vB = fmaxf(t, NEG * t);
            hB.u = *(const ushort4*)(h2 + (size_t)sD * OUTC + c);
        }
        sC = sE; sD = sF;
        float wA = __expf(vcA), wB = __expf(vcB);
        sum += wA + wB;
        a0 = fmaf(wA, __half2float(hcA.h[0]), a0); a0 = fmaf(wB, __half2float(hcB.h[0]), a0);
        a1 = fmaf(wA, __half2float(hcA.h[1]), a1); a1 = fmaf(wB, __half2float(hcB.h[1]), a1);
        a2 = fmaf(wA, __half2float(hcA.h[2]), a2); a2 = fmaf(wB, __half2float(hcB.h[2]), a2);
        a3 = fmaf(wA, __half2float(hcA.h[3]), a3); a3 = fmaf(wB, __half2float(hcB.h[3]), a3);
    }
    if (k < r1) {
        float wA = __expf(vA);
        sum += wA;
        a0 = fmaf(wA, __half2float(hA.h[0]), a0);
        a1 = fmaf(wA, __half2float(hA.h[1]), a1);
        a2 = fmaf(wA, __half2float(hA.h[2]), a2);
        a3 = fmaf(wA, __half2float(hA.h[3]), a3);
    }

    float inv = 1.0f / sum;
    float4 bv = *(const float4*)(b2 + c);
    float4 o;
    o.x = a0 * inv + bv.x; o.y = a1 * inv + bv.y;
    o.z = a2 * inv + bv.z; o.w = a3 * inv + bv.w;
    *(float4*)(out + (size_t)n * OUTC + c) = o;
}

extern "C" void kernel_launch(void* const* d_in, const int* in_sizes, int n_in,
                              void* d_out, int out_size, void* d_ws, size_t ws_size,
                              hipStream_t stream)
{
    const float* x   = (const float*)d_in[0];
    const int*   ei  = (const int*)  d_in[1];
    const float* W1  = (const float*)d_in[2];
    const float* as1 = (const float*)d_in[3];
    const float* ad1 = (const float*)d_in[4];
    const float* b1  = (const float*)d_in[5];
    const float* W2  = (const float*)d_in[6];
    const float* as2 = (const float*)d_in[7];
    const float* ad2 = (const float*)d_in[8];
    const float* b2  = (const float*)d_in[9];
    float* out = (float*)d_out;

    char* wsb = (char*)d_ws;
    const size_t SZ_H1 = (size_t)N_NODES * F1 * sizeof(__half);   // 12.8 MB
    __half* h1h = (__half*)wsb;
    __half* h1b = (__half*)(wsb + SZ_H1);
    float*  als1 = (float*)(wsb + 2 * SZ_H1);                     // N*8
    float*  ald1 = als1 + (size_t)N_NODES * 8;                    // N*8
    __half* h2f  = (__half*)(ald1 + (size_t)N_NODES * 8);         // N*16 fp16
    float*  als2 = (float*)(h2f + (size_t)N_NODES * OUTC);        // N
    float*  ald2 = als2 + N_NODES;                                // N
    __half* w1t  = (__half*)(ald2 + N_NODES);                     // 128*128 fp16
    __half* waT  = w1t + INC * F1;                                // 16*128 fp16
    int*    tmp  = (int*)(waT + 16 * INC);                        // NE ints (packed)
    int*    cnt  = tmp + NE;                                      // NBKT*NPART
    int*    csr  = cnt + NBKT * NPART;                            // NE
    int*    rowstart = csr + NE;                                  // N+1
    int*    bsum = rowstart + N_NODES + 1;                        // NBKT

    // ---- CSR build + weight prep: single cooperative kernel ----
    {
        void* args[] = { (void*)&ei, (void*)&cnt, (void*)&bsum, (void*)&tmp,
                         (void*)&rowstart, (void*)&csr, (void*)&W1,
                         (void*)&as1, (void*)&ad1, (void*)&w1t, (void*)&waT };
        hipLaunchCooperativeKernel((const void*)csr_build_kernel,
                                   dim3(NBKT), dim3(256), args, 0, stream);
    }

    // ---- layer 1 ----
    node1_kernel<<<(N_NODES + 63) / 64, 256, 0, stream>>>(x, w1t, waT, h1h, als1, ald1);
    agg1_kernel<<<N_NODES / 16, 256, 0, stream>>>(rowstart, csr, h1h, als1, ald1, b1, h1b);

    // ---- layer 2 ----
    node2_kernel<<<(N_NODES + 255) / 256, 256, 0, stream>>>(h1b, W2, as2, ad2, h2f, als2, ald2);
    agg2_kernel<<<(N_NODES + 63) / 64, 256, 0, stream>>>(rowstart, csr, h2f, als2, ald2, b2, out);
}

// Round 17
// 221.473 us; speedup vs baseline: 1.5023x; 1.5023x over previous
//
#include <hip/hip_runtime.h>
#include <hip/hip_fp16.h>
#include <math.h>

#define N_NODES 50000
#define NE      800000
#define INC     128
#define F1      128     // HEADS*HID
#define HEADS   8
#define HID     16
#define OUTC    16
#define NEG     0.2f
#define NBKT    196      // (N_NODES+255)>>8
#define NPART   128      // partition blocks
#define N1BLK   ((N_NODES + 63) / 64)   // 782 node1 blocks

union H4 { ushort4 u; __half h[4]; };
union H8 { uint4 u; __half h[8]; };

typedef _Float16 f16x8 __attribute__((ext_vector_type(8)));
typedef float    f32x4 __attribute__((ext_vector_type(4)));

// ==== fused: per-block dst histogram (blocks 0..127) + weight prep (128..199)
__global__ __launch_bounds__(256) void prep_kernel(const int* __restrict__ ei,
                                                   int* __restrict__ cnt,
                                                   const float* __restrict__ W1,
                                                   const float* __restrict__ as1,
                                                   const float* __restrict__ ad1,
                                                   __half* __restrict__ W1t,
                                                   __half* __restrict__ waT) {
    __shared__ int h[NBKT];
    int b = blockIdx.x, tid = threadIdx.x;
    if (b < NPART) {                     // edge histogram by dst>>8
        for (int i = tid; i < NBKT; i += 256) h[i] = 0;
        __syncthreads();
        for (int e = b * 256 + tid; e < NE; e += NPART * 256)
            atomicAdd(&h[ei[NE + e] >> 8], 1);
        __syncthreads();
        for (int i = tid; i < NBKT; i += 256) cnt[i * NPART + b] = h[i];
    } else if (b < NPART + 64) {         // W1 transpose to fp16
        int i = (b - NPART) * 256 + tid;
        int k = i >> 7, nn = i & 127;
        W1t[nn * 128 + k] = __float2half(W1[k * 128 + nn]);
    } else {                             // folded attention matrix Wa
        int i = (b - NPART - 64) * 256 + tid;   // 0..2047
        int col = i & 15, k = i >> 4;
        int hh = col & 7;
        const float* av = (col < 8) ? as1 : ad1;
        float s = 0.f;
        #pragma unroll
        for (int cc = 0; cc < 16; ++cc)
            s += W1[k * 128 + hh * 16 + cc] * av[hh * 16 + cc];
        waT[col * 128 + k] = __float2half(s);   // B-frag layout [n=col][k]
    }
}

__global__ __launch_bounds__(1024) void scan25k(int* __restrict__ cnt) {
    __shared__ int part[1024];
    const int TOT = NBKT * NPART;             // 25088
    const int PER = (TOT + 1023) / 1024;      // 25
    int tid = threadIdx.x;
    int base = tid * PER;
    int s = 0;
    for (int i = 0; i < PER; ++i) {
        int idx = base + i;
        if (idx < TOT) s += cnt[idx];
    }
    part[tid] = s; __syncthreads();
    for (int off = 1; off < 1024; off <<= 1) {
        int t = (tid >= off) ? part[tid - off] : 0;
        __syncthreads();
        part[tid] += t;
        __syncthreads();
    }
    int run = part[tid] - s;
    for (int i = 0; i < PER; ++i) {
        int idx = base + i;
        if (idx < TOT) { int v = cnt[idx]; cnt[idx] = run; run += v; }
    }
}

// ==== fused: edge scatter (blocks 0..127) + Layer-1 MFMA GEMM (128..909) ====
// Independent work items: scatter needs scanned cnt; node1 needs w1t/waT.
// The latency-bound scatter hides under node1's MFMA compute.
__global__ __launch_bounds__(256) void scatter_node1_kernel(
    const int* __restrict__ ei, const int* __restrict__ cnt, int* __restrict__ tmp,
    const float* __restrict__ x, const __half* __restrict__ W1t,
    const __half* __restrict__ waT,
    __half* __restrict__ hfeat, float* __restrict__ als, float* __restrict__ ald)
{
    __shared__ _Float16 Xh[64 * 136];    // 17.4 KB
    __shared__ _Float16 Wt[128 * 136];   // 34.8 KB (pad 8 halves/row)
    int b = blockIdx.x, tid = threadIdx.x;

    if (b < NPART) {                     // ---- edge scatter branch ----
        int* cur = (int*)Xh;             // alias LDS (only need NBKT ints)
        for (int i = tid; i < NBKT; i += 256) cur[i] = cnt[i * NPART + b];
        __syncthreads();
        for (int e = b * 256 + tid; e < NE; e += NPART * 256) {
            int s = ei[e], d = ei[NE + e];
            int p = atomicAdd(&cur[d >> 8], 1);
            tmp[p] = s | ((d & 255) << 16);   // s in 0..15, d&255 in 16..23
        }
        return;
    }

    // ---- node1 branch ----
    int n0 = (b - NPART) * 64;

    for (int idx = tid; idx < 128 * 16; idx += 256) {   // 16 x uint4 per row
        int row = idx >> 4, c8 = (idx & 15) * 8;
        *(uint4*)(&Wt[row * 136 + c8]) = ((const uint4*)W1t)[idx];
    }
    for (int idx = tid; idx < 64 * 32; idx += 256) {
        int m = idx >> 5, f4 = idx & 31;
        int n = n0 + m;
        float4 v = (n < N_NODES) ? ((const float4*)(x + (size_t)n * INC))[f4]
                                 : make_float4(0.f, 0.f, 0.f, 0.f);
        union { unsigned long long u; _Float16 h[4]; } p;
        p.h[0] = (_Float16)v.x; p.h[1] = (_Float16)v.y;
        p.h[2] = (_Float16)v.z; p.h[3] = (_Float16)v.w;
        *(unsigned long long*)(&Xh[m * 136 + f4 * 4]) = p.u;
    }
    __syncthreads();

    int wave = tid >> 6, lane = tid & 63;
    int colL = lane & 15, q = lane >> 4;
    int nb = wave * 32;

    f32x4 acc[4][2];
    #pragma unroll
    for (int mt = 0; mt < 4; ++mt)
        #pragma unroll
        for (int nt = 0; nt < 2; ++nt)
            acc[mt][nt] = (f32x4){0.f, 0.f, 0.f, 0.f};
    f32x4 acc2 = (f32x4){0.f, 0.f, 0.f, 0.f};   // logits, mt = wave

    #pragma unroll
    for (int kb = 0; kb < 4; ++kb) {
        int ko = kb * 32 + q * 8;
        f16x8 b0 = *(const f16x8*)(&Wt[(nb +  0 + colL) * 136 + ko]);
        f16x8 b1 = *(const f16x8*)(&Wt[(nb + 16 + colL) * 136 + ko]);
        #pragma unroll
        for (int mt = 0; mt < 4; ++mt) {
            f16x8 a = *(const f16x8*)(&Xh[(mt * 16 + colL) * 136 + ko]);
            acc[mt][0] = __builtin_amdgcn_mfma_f32_16x16x32_f16(a, b0, acc[mt][0], 0, 0, 0);
            acc[mt][1] = __builtin_amdgcn_mfma_f32_16x16x32_f16(a, b1, acc[mt][1], 0, 0, 0);
        }
        f16x8 bw = *(const f16x8*)(waT + colL * 128 + ko);           // global, L2-hot
        f16x8 aw = *(const f16x8*)(&Xh[(wave * 16 + colL) * 136 + ko]);
        acc2 = __builtin_amdgcn_mfma_f32_16x16x32_f16(aw, bw, acc2, 0, 0, 0);
    }

    // h stores (fp16)
    #pragma unroll
    for (int nt = 0; nt < 2; ++nt) {
        int col = nb + nt * 16 + colL;
        #pragma unroll
        for (int mt = 0; mt < 4; ++mt) {
            f32x4 d = acc[mt][nt];
            #pragma unroll
            for (int r = 0; r < 4; ++r) {
                int node = n0 + mt * 16 + q * 4 + r;
                if (node < N_NODES) hfeat[(size_t)node * F1 + col] = __float2half(d[r]);
            }
        }
    }
    // logit stores: split src/dst arrays (32B/node granularity for the gather)
    #pragma unroll
    for (int r = 0; r < 4; ++r) {
        int node = n0 + wave * 16 + q * 4 + r;
        if (node < N_NODES) {
            if (colL < 8) als[node * 8 + colL] = acc2[r];
            else          ald[node * 8 + (colL - 8)] = acc2[r];
        }
    }
}

__global__ __launch_bounds__(256) void bucket_sort(const int* __restrict__ tmp,
                                                   const int* __restrict__ cnt,
                                                   int* __restrict__ rowstart,
                                                   int* __restrict__ csr) {
    __shared__ int h[256];
    int b = blockIdx.x, tid = threadIdx.x;
    int base = cnt[b * NPART];
    int end  = (b == NBKT - 1) ? NE : cnt[(b + 1) * NPART];
    h[tid] = 0; __syncthreads();
    for (int i = base + tid; i < end; i += 256)
        atomicAdd(&h[(tmp[i] >> 16) & 255], 1);
    __syncthreads();
    int v = h[tid];
    for (int off = 1; off < 256; off <<= 1) {
        int t = (tid >= off) ? h[tid - off] : 0;
        __syncthreads();
        h[tid] += t;
        __syncthreads();
    }
    int excl = h[tid] - v;
    int n = (b << 8) + tid;
    if (n <= N_NODES) rowstart[n] = base + excl;
    __syncthreads();
    h[tid] = excl;
    __syncthreads();
    for (int i = base + tid; i < end; i += 256) {
        int e = tmp[i];
        int p = base + atomicAdd(&h[(e >> 16) & 255], 1);
        csr[p] = e & 0xFFFF;
    }
}

// ------ Layer 1 gather: 16 lanes/node, 8 fp16/lane, depth-2 static pipeline -
__global__ __launch_bounds__(256) void agg1_kernel(
    const int* __restrict__ rowstart, const int* __restrict__ csr,
    const __half* __restrict__ h1, const float* __restrict__ als,
    const float* __restrict__ ald, const float* __restrict__ b1,
    __half* __restrict__ hout)
{
    int tid = threadIdx.x;
    int n = blockIdx.x * 16 + (tid >> 4);
    int lane = tid & 15;
    int c = lane * 8;
    int head = lane >> 1;
    float aldn = ald[n * 8 + head];
    float v0 = als[n * 8 + head] + aldn;
    v0 = fmaxf(v0, NEG * v0);
    float w0 = __expf(v0);
    float sum = w0;
    float a[8];
    {
        H8 hs; hs.u = *(const uint4*)(h1 + (size_t)n * F1 + c);
        #pragma unroll
        for (int i = 0; i < 8; ++i) a[i] = w0 * __half2float(hs.h[i]);
    }
    int r0 = rowstart[n], r1 = rowstart[n + 1];

    float vA = 0.f, vB = 0.f;
    H8 hA, hB; hA.u = make_uint4(0,0,0,0); hB.u = hA.u;
    int sC = 0, sD = 0;
    if (r0 < r1) {
        int s = csr[r0];
        float t = als[s * 8 + head] + aldn;
        vA = fmaxf(t, NEG * t);
        hA.u = *(const uint4*)(h1 + (size_t)s * F1 + c);
    }
    if (r0 + 1 < r1) {
        int s = csr[r0 + 1];
        float t = als[s * 8 + head] + aldn;
        vB = fmaxf(t, NEG * t);
        hB.u = *(const uint4*)(h1 + (size_t)s * F1 + c);
    }
    if (r0 + 2 < r1) sC = csr[r0 + 2];
    if (r0 + 3 < r1) sD = csr[r0 + 3];

    int k = r0;
    for (; k + 1 < r1; k += 2) {
        float vcA = vA, vcB = vB;
        H8 hcA = hA, hcB = hB;
        int sE = (k + 4 < r1) ? csr[k + 4] : 0;
        int sF = (k + 5 < r1) ? csr[k + 5] : 0;
        if (k + 2 < r1) {
            float t = als[sC * 8 + head] + aldn;
            vA = fmaxf(t, NEG * t);
            hA.u = *(const uint4*)(h1 + (size_t)sC * F1 + c);
        }
        if (k + 3 < r1) {
            float t = als[sD * 8 + head] + aldn;
            vB = fmaxf(t, NEG * t);
            hB.u = *(const uint4*)(h1 + (size_t)sD * F1 + c);
        }
        sC = sE; sD = sF;
        float wA = __expf(vcA), wB = __expf(vcB);
        sum += wA + wB;
        #pragma unroll
        for (int i = 0; i < 8; ++i) {
            a[i] = fmaf(wA, __half2float(hcA.h[i]), a[i]);
            a[i] = fmaf(wB, __half2float(hcB.h[i]), a[i]);
        }
    }
    if (k < r1) {                      // odd tail: consume slot A
        float wA = __expf(vA);
        sum += wA;
        #pragma unroll
        for (int i = 0; i < 8; ++i) a[i] = fmaf(wA, __half2float(hA.h[i]), a[i]);
    }

    float inv = 1.0f / sum;
    H8 t;
    #pragma unroll
    for (int i = 0; i < 8; ++i) {
        float o = a[i] * inv + b1[c + i];
        o = o > 0.f ? o : (__expf(o) - 1.0f);
        t.h[i] = __float2half(o);
    }
    *(uint4*)(hout + (size_t)n * F1 + c) = t.u;
}

// ---------------- Layer 2: GEMM (h1' @ W2) + logits, fp16 in/out ----------
__global__ __launch_bounds__(256) void node2_kernel(
    const __half* __restrict__ h1, const float* __restrict__ W2,
    const float* __restrict__ a_s, const float* __restrict__ a_d,
    __half* __restrict__ h2, float* __restrict__ als2, float* __restrict__ ald2)
{
    __shared__ float W2l[F1 * OUTC];   // 8 KB
    for (int i = threadIdx.x; i < F1 * OUTC; i += 256) W2l[i] = W2[i];
    __syncthreads();
    int n = blockIdx.x * blockDim.x + threadIdx.x;
    if (n >= N_NODES) return;

    float o[OUTC];
    #pragma unroll
    for (int c = 0; c < OUTC; ++c) o[c] = 0.f;
    const uint4* xr = (const uint4*)(h1 + (size_t)n * F1);
    for (int k8 = 0; k8 < 16; ++k8) {
        H8 xv; xv.u = xr[k8];
        int k = k8 * 8;
        #pragma unroll
        for (int j = 0; j < 8; ++j) {
            float xf = __half2float(xv.h[j]);
            #pragma unroll
            for (int c = 0; c < OUTC; ++c)
                o[c] = fmaf(xf, W2l[(k + j) * OUTC + c], o[c]);
        }
    }
    H8 s0, s1;
    #pragma unroll
    for (int j = 0; j < 8; ++j) { s0.h[j] = __float2half(o[j]); s1.h[j] = __float2half(o[8 + j]); }
    uint4* h2o = (uint4*)(h2 + (size_t)n * OUTC);
    h2o[0] = s0.u; h2o[1] = s1.u;
    float ps = 0.f, pd = 0.f;
    #pragma unroll
    for (int c = 0; c < OUTC; ++c) { ps += o[c] * a_s[c]; pd += o[c] * a_d[c]; }
    als2[n] = ps; ald2[n] = pd;
}

// ------ Layer 2 gather: 4 lanes/node, 4 fp16/lane, depth-2 static pipeline -
__global__ __launch_bounds__(256) void agg2_kernel(
    const int* __restrict__ rowstart, const int* __restrict__ csr,
    const __half* __restrict__ h2, const float* __restrict__ als,
    const float* __restrict__ ald, const float* __restrict__ b2,
    float* __restrict__ out)
{
    int tid = threadIdx.x;
    int n = blockIdx.x * 64 + (tid >> 2);
    if (n >= N_NODES) return;
    int c = (tid & 3) * 4;
    float aldn = ald[n];
    float v0 = als[n] + aldn;
    v0 = fmaxf(v0, NEG * v0);
    float w0 = __expf(v0);
    float sum = w0;
    H4 hs; hs.u = *(const ushort4*)(h2 + (size_t)n * OUTC + c);
    float a0 = w0 * __half2float(hs.h[0]), a1 = w0 * __half2float(hs.h[1]);
    float a2 = w0 * __half2float(hs.h[2]), a3 = w0 * __half2float(hs.h[3]);
    int r0 = rowstart[n], r1 = rowstart[n + 1];

    float vA = 0.f, vB = 0.f;
    H4 hA, hB; hA.u = make_ushort4(0,0,0,0); hB.u = hA.u;
    int sC = 0, sD = 0;
    if (r0 < r1) {
        int s = csr[r0];
        float t = als[s] + aldn;
        vA = fmaxf(t, NEG * t);
        hA.u = *(const ushort4*)(h2 + (size_t)s * OUTC + c);
    }
    if (r0 + 1 < r1) {
        int s = csr[r0 + 1];
        float t = als[s] + aldn;
        vB = fmaxf(t, NEG * t);
        hB.u = *(const ushort4*)(h2 + (size_t)s * OUTC + c);
    }
    if (r0 + 2 < r1) sC = csr[r0 + 2];
    if (r0 + 3 < r1) sD = csr[r0 + 3];

    int k = r0;
    for (; k + 1 < r1; k += 2) {
        float vcA = vA, vcB = vB;
        H4 hcA = hA, hcB = hB;
        int sE = (k + 4 < r1) ? csr[k + 4] : 0;
        int sF = (k + 5 < r1) ? csr[k + 5] : 0;
        if (k + 2 < r1) {
            float t = als[sC] + aldn;
            vA = fmaxf(t, NEG * t);
            hA.u = *(const ushort4*)(h2 + (size_t)sC * OUTC + c);
        }
        if (k + 3 < r1) {
            float t = als[sD] + aldn;
            vB = fmaxf(t, NEG * t);
            hB.u = *(const ushort4*)(h2 + (size_t)sD * OUTC + c);
        }
        sC = sE; sD = sF;
        float wA = __expf(vcA), wB = __expf(vcB);
        sum += wA + wB;
        a0 = fmaf(wA, __half2float(hcA.h[0]), a0); a0 = fmaf(wB, __half2float(hcB.h[0]), a0);
        a1 = fmaf(wA, __half2float(hcA.h[1]), a1); a1 = fmaf(wB, __half2float(hcB.h[1]), a1);
        a2 = fmaf(wA, __half2float(hcA.h[2]), a2); a2 = fmaf(wB, __half2float(hcB.h[2]), a2);
        a3 = fmaf(wA, __half2float(hcA.h[3]), a3); a3 = fmaf(wB, __half2float(hcB.h[3]), a3);
    }
    if (k < r1) {
        float wA = __expf(vA);
        sum += wA;
        a0 = fmaf(wA, __half2float(hA.h[0]), a0);
        a1 = fmaf(wA, __half2float(hA.h[1]), a1);
        a2 = fmaf(wA, __half2float(hA.h[2]), a2);
        a3 = fmaf(wA, __half2float(hA.h[3]), a3);
    }

    float inv = 1.0f / sum;
    float4 bv = *(const float4*)(b2 + c);
    float4 o;
    o.x = a0 * inv + bv.x; o.y = a1 * inv + bv.y;
    o.z = a2 * inv + bv.z; o.w = a3 * inv + bv.w;
    *(float4*)(out + (size_t)n * OUTC + c) = o;
}

extern "C" void kernel_launch(void* const* d_in, const int* in_sizes, int n_in,
                              void* d_out, int out_size, void* d_ws, size_t ws_size,
                              hipStream_t stream)
{
    const float* x   = (const float*)d_in[0];
    const int*   ei  = (const int*)  d_in[1];
    const float* W1  = (const float*)d_in[2];
    const float* as1 = (const float*)d_in[3];
    const float* ad1 = (const float*)d_in[4];
    const float* b1  = (const float*)d_in[5];
    const float* W2  = (const float*)d_in[6];
    const float* as2 = (const float*)d_in[7];
    const float* ad2 = (const float*)d_in[8];
    const float* b2  = (const float*)d_in[9];
    float* out = (float*)d_out;

    char* wsb = (char*)d_ws;
    const size_t SZ_H1 = (size_t)N_NODES * F1 * sizeof(__half);   // 12.8 MB
    __half* h1h = (__half*)wsb;
    __half* h1b = (__half*)(wsb + SZ_H1);
    float*  als1 = (float*)(wsb + 2 * SZ_H1);                     // N*8
    float*  ald1 = als1 + (size_t)N_NODES * 8;                    // N*8
    __half* h2f  = (__half*)(ald1 + (size_t)N_NODES * 8);         // N*16 fp16
    float*  als2 = (float*)(h2f + (size_t)N_NODES * OUTC);        // N
    float*  ald2 = als2 + N_NODES;                                // N
    __half* w1t  = (__half*)(ald2 + N_NODES);                     // 128*128 fp16
    __half* waT  = w1t + INC * F1;                                // 16*128 fp16
    int*    tmp  = (int*)(waT + 16 * INC);                        // NE ints (packed)
    int*    cnt  = tmp + NE;                                      // NBKT*NPART
    int*    csr  = cnt + NBKT * NPART;                            // NE
    int*    rowstart = csr + NE;                                  // N+1

    // ---- CSR build + weight prep; scatter hidden under node1 ----
    prep_kernel <<<NPART + 72, 256, 0, stream>>>(ei, cnt, W1, as1, ad1, w1t, waT);
    scan25k     <<<1, 1024, 0, stream>>>(cnt);
    scatter_node1_kernel<<<NPART + N1BLK, 256, 0, stream>>>(ei, cnt, tmp,
                                                            x, w1t, waT, h1h, als1, ald1);
    bucket_sort <<<NBKT, 256, 0, stream>>>(tmp, cnt, rowstart, csr);

    // ---- layer 1 gather ----
    agg1_kernel<<<N_NODES / 16, 256, 0, stream>>>(rowstart, csr, h1h, als1, ald1, b1, h1b);

    // ---- layer 2 ----
    node2_kernel<<<(N_NODES + 255) / 256, 256, 0, stream>>>(h1b, W2, as2, ad2, h2f, als2, ald2);
    agg2_kernel<<<(N_NODES + 63) / 64, 256, 0, stream>>>(rowstart, csr, h2f, als2, ald2, b2, out);
}